// Round 7
// baseline (122.733 us; speedup 1.0000x reference)
//
#include <hip/hip_runtime.h>
#include <math.h>

#define BB 256
#define NN 1024
#define DD 128
#define NCHUNK 4
#define ROWS (NN / NCHUNK)   // 256

// workspace layout (in floats)
#define PA_OFF   0
#define PC_OFF   (NCHUNK*BB*DD)            // 131072
#define PCNT_OFF (2*NCHUNK*BB*DD)          // 262144
#define U_OFF    (PCNT_OFF + NCHUNK*BB)    // 263168
#define V_OFF    (U_OFF + BB*DD)           // 295936
// total = 328704 floats = 1.32 MB

// ---------------------------------------------------------------------------
// Kernel 1: masked streaming reductions over N.
//   P_A[chunk][b][k] = sum_{n in chunk} (mi-mj) * d[b,n,k]
//   P_C[chunk][b][k] = sum_{n in chunk} (mi*si - mj*sj)[b,n,k]
//   P_cnt[chunk][b]  = sum_{n in chunk} (mi-mj)
// grid = (NCHUNK, BB), block = 512 (32 lanes x 16 row-groups).
// Masks staged in LDS; main loop unrolled x2 with 6 batched float4 loads.
// ---------------------------------------------------------------------------
__global__ __launch_bounds__(512, 8) void k1_reduce(
    const float* __restrict__ d, const float* __restrict__ si,
    const float* __restrict__ sj, const void* __restrict__ miv,
    const void* __restrict__ mjv, float* __restrict__ ws)
{
    const int chunk = blockIdx.x;
    const int b     = blockIdx.y;
    const int t     = threadIdx.x;
    const int lane  = t & 31;   // float4 column group: cols lane*4 .. +3
    const int rg    = t >> 5;   // row group 0..15

    // ---- mask dtype auto-detect (bool bytes vs int32) ----
    __shared__ int s_mode;
    if (t == 0) s_mode = 0;
    __syncthreads();
    if (t < 256) {
        const unsigned int* a = (const unsigned int*)miv;
        const unsigned int* c = (const unsigned int*)mjv;
        if ((a[t] | c[t]) > 1u) s_mode = 1;  // bytes of 0/1 packed in a word
    }
    __syncthreads();
    const bool bytes_mode = (s_mode != 0);

    // ---- stage this chunk's masks to LDS as (fi, fj) pairs ----
    __shared__ float2 s_m[ROWS];
    const int    n0      = chunk * ROWS;
    const size_t rowbase = (size_t)b * NN;
    if (t < ROWS) {
        const size_t m = rowbase + (size_t)(n0 + t);
        float fi, fj;
        if (bytes_mode) {
            fi = (float)((const unsigned char*)miv)[m];
            fj = (float)((const unsigned char*)mjv)[m];
        } else {
            fi = (float)((const int*)miv)[m];
            fj = (float)((const int*)mjv)[m];
        }
        s_m[t] = make_float2(fi, fj);
    }
    __syncthreads();

    float aA[4] = {0.f, 0.f, 0.f, 0.f};
    float aC[4] = {0.f, 0.f, 0.f, 0.f};
    float cnt   = 0.f;

    const size_t base = (rowbase + (size_t)n0) * DD + (size_t)lane * 4;

    // rows handled by this thread: r = it*16 + rg, it = 0..15 (unroll x2).
    // Within a wave (rgs 2w, 2w+1) each float4 load covers 2 adjacent rows
    // = 1 KB contiguous.
    for (int it = 0; it < 16; it += 2) {
        const int r0 = it * 16 + rg;
        const int r1 = r0 + 16;
        const size_t off0 = base + (size_t)r0 * DD;
        const size_t off1 = base + (size_t)r1 * DD;
        // batch all 6 loads before consuming
        const float4 d40 = *(const float4*)(d  + off0);
        const float4 x40 = *(const float4*)(si + off0);
        const float4 y40 = *(const float4*)(sj + off0);
        const float4 d41 = *(const float4*)(d  + off1);
        const float4 x41 = *(const float4*)(si + off1);
        const float4 y41 = *(const float4*)(sj + off1);
        const float2 m0 = s_m[r0];
        const float2 m1 = s_m[r1];
        const float wd0 = m0.x - m0.y;
        const float wd1 = m1.x - m1.y;

        aA[0] = fmaf(wd0, d40.x, aA[0]);
        aA[1] = fmaf(wd0, d40.y, aA[1]);
        aA[2] = fmaf(wd0, d40.z, aA[2]);
        aA[3] = fmaf(wd0, d40.w, aA[3]);
        aC[0] = fmaf(m0.x, x40.x, aC[0]); aC[0] = fmaf(-m0.y, y40.x, aC[0]);
        aC[1] = fmaf(m0.x, x40.y, aC[1]); aC[1] = fmaf(-m0.y, y40.y, aC[1]);
        aC[2] = fmaf(m0.x, x40.z, aC[2]); aC[2] = fmaf(-m0.y, y40.z, aC[2]);
        aC[3] = fmaf(m0.x, x40.w, aC[3]); aC[3] = fmaf(-m0.y, y40.w, aC[3]);

        aA[0] = fmaf(wd1, d41.x, aA[0]);
        aA[1] = fmaf(wd1, d41.y, aA[1]);
        aA[2] = fmaf(wd1, d41.z, aA[2]);
        aA[3] = fmaf(wd1, d41.w, aA[3]);
        aC[0] = fmaf(m1.x, x41.x, aC[0]); aC[0] = fmaf(-m1.y, y41.x, aC[0]);
        aC[1] = fmaf(m1.x, x41.y, aC[1]); aC[1] = fmaf(-m1.y, y41.y, aC[1]);
        aC[2] = fmaf(m1.x, x41.z, aC[2]); aC[2] = fmaf(-m1.y, y41.z, aC[2]);
        aC[3] = fmaf(m1.x, x41.w, aC[3]); aC[3] = fmaf(-m1.y, y41.w, aC[3]);

        cnt += wd0 + wd1;   // identical across the 32 lanes of a row-group
    }

    // ---- reduce the 16 row-groups (t strides of 32); [9] pads bank conflicts
    __shared__ float red[512][9];
    #pragma unroll
    for (int i = 0; i < 4; ++i) { red[t][i] = aA[i]; red[t][4 + i] = aC[i]; }
    red[t][8] = cnt;
    __syncthreads();
    if (t < 256) {
        #pragma unroll
        for (int i = 0; i < 9; ++i) red[t][i] += red[t + 256][i];
    }
    __syncthreads();
    if (t < 128) {
        #pragma unroll
        for (int i = 0; i < 9; ++i) red[t][i] += red[t + 128][i];
    }
    __syncthreads();
    if (t < 64) {
        #pragma unroll
        for (int i = 0; i < 9; ++i) red[t][i] += red[t + 64][i];
    }
    __syncthreads();
    if (t < 32) {
        #pragma unroll
        for (int i = 0; i < 9; ++i) red[t][i] += red[t + 32][i];
        float* PA = ws + PA_OFF + ((size_t)chunk * BB + b) * DD;
        float* PC = ws + PC_OFF + ((size_t)chunk * BB + b) * DD;
        #pragma unroll
        for (int i = 0; i < 4; ++i) {
            PA[t * 4 + i] = red[t][i];
            PC[t * 4 + i] = red[t][4 + i];
        }
        if (t == 0) ws[PCNT_OFF + chunk * BB + b] = red[0][8];
        // cnt is identical across the 32 lanes of each row-group, and the
        // tree above summed across the 16 row-groups only -> red[0][8] is
        // exactly sum_n (mi-mj) for this chunk.
    }
}

// ---------------------------------------------------------------------------
// Kernel 2: M = relu(dm @ W1 + b1) fused with the w2 contraction:
//   u[b][p] = sum_q relu(dm[b]·W1[:,p*128+q] + b1[p*128+q]) * w2a[q]
//   v[b][p] = same with w2b
// grid = (128 p-tiles, 2 b-groups), block = 256 = 16 tx (q) x 16 ty (b).
// Each thread: 4 b x 8 q register tile over K=128.
// ---------------------------------------------------------------------------
__global__ __launch_bounds__(256) void k2_gemm(
    const float* __restrict__ d, const float* __restrict__ W1,
    const float* __restrict__ b1, const float* __restrict__ W2,
    float* __restrict__ ws)
{
    const int p  = blockIdx.x;      // output row of M (0..127)
    const int bg = blockIdx.y;      // batch group (0..1), 128 b each
    const int t  = threadIdx.x;
    const int tx = t & 15;          // q group: q0 = tx*8
    const int ty = t >> 4;          // b group: bb0 = ty*4

    __shared__ float w1s[128][128];  // [k][q]  64 KB
    __shared__ float dms[64][132];   // [bb][k] padded, ~34 KB
    __shared__ float b1s[128];
    __shared__ float w2as[128];
    __shared__ float w2bs[128];

    // stage W1 tile (coalesced: consecutive t -> consecutive q)
    for (int idx = t; idx < 128 * 128; idx += 256) {
        const int k = idx >> 7, q = idx & 127;
        w1s[k][q] = W1[(size_t)k * 16384 + p * 128 + q];
    }
    if (t < 128) {
        b1s[t]  = b1[p * 128 + t];
        w2as[t] = W2[t];
        w2bs[t] = W2[128 + t];
    }

    const int q0  = tx * 8;
    const int bb0 = ty * 4;

    for (int sc = 0; sc < 2; ++sc) {   // two sub-chunks of 64 batches
        const int b0 = bg * 128 + sc * 64;
        __syncthreads();   // protect dms reuse; also fences w1s staging (sc=0)
        for (int idx = t; idx < 64 * 128; idx += 256) {
            const int bb = idx >> 7, k = idx & 127;
            dms[bb][k] = d[(size_t)(b0 + bb) * NN * DD + k];  // d[b][0][k]
        }
        __syncthreads();

        float acc[4][8];
        #pragma unroll
        for (int i = 0; i < 4; ++i) {
            #pragma unroll
            for (int j = 0; j < 8; ++j) acc[i][j] = 0.f;
        }

        #pragma unroll 4
        for (int k = 0; k < 128; ++k) {
            float a0 = dms[bb0 + 0][k];
            float a1 = dms[bb0 + 1][k];
            float a2 = dms[bb0 + 2][k];
            float a3 = dms[bb0 + 3][k];
            const float4 wlo = *(const float4*)&w1s[k][q0];
            const float4 whi = *(const float4*)&w1s[k][q0 + 4];
            const float wq[8] = {wlo.x, wlo.y, wlo.z, wlo.w,
                                 whi.x, whi.y, whi.z, whi.w};
            #pragma unroll
            for (int j = 0; j < 8; ++j) {
                acc[0][j] = fmaf(a0, wq[j], acc[0][j]);
                acc[1][j] = fmaf(a1, wq[j], acc[1][j]);
                acc[2][j] = fmaf(a2, wq[j], acc[2][j]);
                acc[3][j] = fmaf(a3, wq[j], acc[3][j]);
            }
        }

        // relu + contract over this thread's 8 q's
        float uacc[4] = {0.f, 0.f, 0.f, 0.f};
        float vacc[4] = {0.f, 0.f, 0.f, 0.f};
        #pragma unroll
        for (int j = 0; j < 8; ++j) {
            const float bias = b1s[q0 + j];
            const float wa = w2as[q0 + j];
            const float wb = w2bs[q0 + j];
            #pragma unroll
            for (int i = 0; i < 4; ++i) {
                float g = fmaxf(acc[i][j] + bias, 0.f);
                uacc[i] += g * wa;
                vacc[i] += g * wb;
            }
        }

        // reduce over the 16 tx threads (lane groups of 16 within the wave)
        #pragma unroll
        for (int off = 8; off > 0; off >>= 1) {
            #pragma unroll
            for (int i = 0; i < 4; ++i) {
                uacc[i] += __shfl_down(uacc[i], off, 16);
                vacc[i] += __shfl_down(vacc[i], off, 16);
            }
        }
        if (tx == 0) {
            const int bbase = b0 + bb0;
            #pragma unroll
            for (int i = 0; i < 4; ++i) {
                ws[U_OFF + (size_t)(bbase + i) * DD + p] = uacc[i];
                ws[V_OFF + (size_t)(bbase + i) * DD + p] = vacc[i];
            }
        }
    }
}

// ---------------------------------------------------------------------------
// Kernel 3: per-batch score assembly + sigmoid.
//   out[b] = sigmoid( Adiff·u + Cdiff·v + b2*cntdiff )
// grid = 256, block = 64 (one wave per batch).
// ---------------------------------------------------------------------------
__global__ __launch_bounds__(64) void k3_final(
    const float* __restrict__ ws, const float* __restrict__ b2p,
    float* __restrict__ out)
{
    const int b = blockIdx.x;
    const int l = threadIdx.x;

    float s = 0.f;
    #pragma unroll
    for (int rep = 0; rep < 2; ++rep) {
        const int k = l + rep * 64;
        float A = 0.f, C = 0.f;
        #pragma unroll
        for (int c = 0; c < NCHUNK; ++c) {
            A += ws[PA_OFF + ((size_t)c * BB + b) * DD + k];
            C += ws[PC_OFF + ((size_t)c * BB + b) * DD + k];
        }
        s += A * ws[U_OFF + (size_t)b * DD + k]
           + C * ws[V_OFF + (size_t)b * DD + k];
    }
    #pragma unroll
    for (int off = 32; off > 0; off >>= 1) s += __shfl_down(s, off, 64);

    if (l == 0) {
        float cnt = 0.f;
        #pragma unroll
        for (int c = 0; c < NCHUNK; ++c) cnt += ws[PCNT_OFF + c * BB + b];
        const float score = s + b2p[0] * cnt;   // SCALING_FACTOR == 1.0
        out[b] = 1.f / (1.f + expf(-score));
    }
}

extern "C" void kernel_launch(void* const* d_in, const int* in_sizes, int n_in,
                              void* d_out, int out_size, void* d_ws, size_t ws_size,
                              hipStream_t stream)
{
    const float* d   = (const float*)d_in[0];
    const float* si  = (const float*)d_in[1];
    const float* sj  = (const float*)d_in[2];
    const void*  mi  = d_in[3];
    const void*  mj  = d_in[4];
    const float* W1  = (const float*)d_in[5];
    const float* b1  = (const float*)d_in[6];
    const float* W2  = (const float*)d_in[7];
    const float* b2  = (const float*)d_in[8];
    float* ws  = (float*)d_ws;
    float* out = (float*)d_out;

    dim3 g1(NCHUNK, BB);
    k1_reduce<<<g1, 512, 0, stream>>>(d, si, sj, mi, mj, ws);
    dim3 g2(128, 2);
    k2_gemm<<<g2, 256, 0, stream>>>(d, W1, b1, W2, ws);
    k3_final<<<BB, 64, 0, stream>>>(ws, b2, out);
}

// Round 8
// 104.079 us; speedup vs baseline: 1.1792x; 1.1792x over previous
//
#include <hip/hip_runtime.h>
#include <math.h>

#define BB 256
#define NN 1024
#define DD 128
#define NCHUNK 4
#define ROWS (NN / NCHUNK)   // 256

// workspace layout (in floats)
#define PA_OFF   0
#define PCI_OFF  (NCHUNK*BB*DD)            // 131072
#define PCJ_OFF  (2*NCHUNK*BB*DD)          // 262144
#define PCNT_OFF (3*NCHUNK*BB*DD)          // 393216
#define U_OFF    (PCNT_OFF + NCHUNK*BB)    // 394240
#define V_OFF    (U_OFF + BB*DD)           // 427008
// total = 459776 floats = 1.84 MB

// ---------------------------------------------------------------------------
// Kernel 1: masked streaming reductions over N, ONE ARRAY PER BLOCK (role).
//   role 0: P_A[chunk][b][k]  = sum_n (mi-mj) * d[b,n,k]   (+ cnt)
//   role 1: P_Ci[chunk][b][k] = sum_n  mi     * si[b,n,k]
//   role 2: P_Cj[chunk][b][k] = sum_n  mj     * sj[b,n,k]
// grid = (NCHUNK, BB, 3), block = 256 (32 lanes x 8 row-groups).
// Pure single-stream float4 pattern per wave; unroll x8 for MLP.
// ---------------------------------------------------------------------------
__global__ __launch_bounds__(256, 6) void k1_stream(
    const float* __restrict__ d, const float* __restrict__ si,
    const float* __restrict__ sj, const void* __restrict__ miv,
    const void* __restrict__ mjv, float* __restrict__ ws)
{
    const int chunk = blockIdx.x;
    const int b     = blockIdx.y;
    const int role  = blockIdx.z;
    const int t     = threadIdx.x;
    const int lane  = t & 31;   // float4 column group: cols lane*4 .. +3
    const int rg    = t >> 5;   // row group 0..7

    // ---- mask dtype auto-detect (bool bytes vs int32) ----
    __shared__ int s_mode;
    if (t == 0) s_mode = 0;
    __syncthreads();
    {
        const unsigned int* a = (const unsigned int*)miv;
        const unsigned int* c = (const unsigned int*)mjv;
        if ((a[t] | c[t]) > 1u) s_mode = 1;  // bytes of 0/1 packed in a word
    }
    __syncthreads();
    const bool bytes_mode = (s_mode != 0);

    // ---- stage this block's per-row weight into LDS (one float per row) ----
    __shared__ float s_w[ROWS];
    const int    n0      = chunk * ROWS;
    const size_t rowbase = (size_t)b * NN;
    {
        const size_t m = rowbase + (size_t)(n0 + t);
        float fi, fj;
        if (bytes_mode) {
            fi = (float)((const unsigned char*)miv)[m];
            fj = (float)((const unsigned char*)mjv)[m];
        } else {
            fi = (float)((const int*)miv)[m];
            fj = (float)((const int*)mjv)[m];
        }
        s_w[t] = (role == 0) ? (fi - fj) : ((role == 1) ? fi : fj);
    }
    __syncthreads();

    const float* src = (role == 0) ? d : ((role == 1) ? si : sj);
    const size_t base = (rowbase + (size_t)n0) * (size_t)DD + (size_t)lane * 4;

    float acc[4] = {0.f, 0.f, 0.f, 0.f};
    float cnt = 0.f;

    // rows for this thread: r = ot*64 + u*8 + rg  (ot=0..3, u=0..7)
    // within a wave (rgs 2w,2w+1) each float4 load covers 2 adjacent rows
    // = 1 KB contiguous; 8 independent loads in flight per wave.
    for (int ot = 0; ot < 4; ++ot) {
        const int r0 = ot * 64 + rg;
        float4 v[8];
        float  w[8];
        #pragma unroll
        for (int u = 0; u < 8; ++u)
            v[u] = *(const float4*)(src + base + (size_t)(r0 + u * 8) * DD);
        #pragma unroll
        for (int u = 0; u < 8; ++u) w[u] = s_w[r0 + u * 8];
        #pragma unroll
        for (int u = 0; u < 8; ++u) {
            acc[0] = fmaf(w[u], v[u].x, acc[0]);
            acc[1] = fmaf(w[u], v[u].y, acc[1]);
            acc[2] = fmaf(w[u], v[u].z, acc[2]);
            acc[3] = fmaf(w[u], v[u].w, acc[3]);
            cnt += w[u];   // identical across the 32 lanes of a row-group
        }
    }

    // ---- reduce the 8 row-groups (t strides of 32) ----
    __shared__ float red[256][5];
    #pragma unroll
    for (int i = 0; i < 4; ++i) red[t][i] = acc[i];
    red[t][4] = cnt;
    __syncthreads();
    if (t < 128) {
        #pragma unroll
        for (int i = 0; i < 5; ++i) red[t][i] += red[t + 128][i];
    }
    __syncthreads();
    if (t < 64) {
        #pragma unroll
        for (int i = 0; i < 5; ++i) red[t][i] += red[t + 64][i];
    }
    __syncthreads();
    if (t < 32) {
        #pragma unroll
        for (int i = 0; i < 5; ++i) red[t][i] += red[t + 32][i];
        const size_t poff = ((role == 0) ? PA_OFF : ((role == 1) ? PCI_OFF
                                                                 : PCJ_OFF))
                          + ((size_t)chunk * BB + b) * DD;
        float* P = ws + poff;
        #pragma unroll
        for (int i = 0; i < 4; ++i) P[t * 4 + i] = red[t][i];
        // cnt: lanes of each row-group hold identical copies; the tree summed
        // across row-groups only, so red[0][4] = sum_n (mi-mj) of this chunk.
        if (t == 0 && role == 0) ws[PCNT_OFF + chunk * BB + b] = red[0][4];
    }
}

// ---------------------------------------------------------------------------
// Kernel 2: M = relu(dm @ W1 + b1) fused with the w2 contraction:
//   u[b][p] = sum_q relu(dm[b]·W1[:,p*128+q] + b1[p*128+q]) * w2a[q]
//   v[b][p] = same with w2b
// grid = (128 p-tiles, 2 b-groups), block = 256 = 16 tx (q) x 16 ty (b).
// ---------------------------------------------------------------------------
__global__ __launch_bounds__(256) void k2_gemm(
    const float* __restrict__ d, const float* __restrict__ W1,
    const float* __restrict__ b1, const float* __restrict__ W2,
    float* __restrict__ ws)
{
    const int p  = blockIdx.x;      // output row of M (0..127)
    const int bg = blockIdx.y;      // batch group (0..1), 128 b each
    const int t  = threadIdx.x;
    const int tx = t & 15;          // q group: q0 = tx*8
    const int ty = t >> 4;          // b group: bb0 = ty*4

    __shared__ float w1s[128][128];  // [k][q]  64 KB
    __shared__ float dms[64][132];   // [bb][k] padded, ~34 KB
    __shared__ float b1s[128];
    __shared__ float w2as[128];
    __shared__ float w2bs[128];

    // stage W1 tile (coalesced: consecutive t -> consecutive q)
    for (int idx = t; idx < 128 * 128; idx += 256) {
        const int k = idx >> 7, q = idx & 127;
        w1s[k][q] = W1[(size_t)k * 16384 + p * 128 + q];
    }
    if (t < 128) {
        b1s[t]  = b1[p * 128 + t];
        w2as[t] = W2[t];
        w2bs[t] = W2[128 + t];
    }

    const int q0  = tx * 8;
    const int bb0 = ty * 4;

    for (int sc = 0; sc < 2; ++sc) {   // two sub-chunks of 64 batches
        const int b0 = bg * 128 + sc * 64;
        __syncthreads();   // protect dms reuse; also fences w1s staging (sc=0)
        for (int idx = t; idx < 64 * 128; idx += 256) {
            const int bb = idx >> 7, k = idx & 127;
            dms[bb][k] = d[(size_t)(b0 + bb) * NN * DD + k];  // d[b][0][k]
        }
        __syncthreads();

        float acc[4][8];
        #pragma unroll
        for (int i = 0; i < 4; ++i) {
            #pragma unroll
            for (int j = 0; j < 8; ++j) acc[i][j] = 0.f;
        }

        #pragma unroll 4
        for (int k = 0; k < 128; ++k) {
            float a0 = dms[bb0 + 0][k];
            float a1 = dms[bb0 + 1][k];
            float a2 = dms[bb0 + 2][k];
            float a3 = dms[bb0 + 3][k];
            const float4 wlo = *(const float4*)&w1s[k][q0];
            const float4 whi = *(const float4*)&w1s[k][q0 + 4];
            const float wq[8] = {wlo.x, wlo.y, wlo.z, wlo.w,
                                 whi.x, whi.y, whi.z, whi.w};
            #pragma unroll
            for (int j = 0; j < 8; ++j) {
                acc[0][j] = fmaf(a0, wq[j], acc[0][j]);
                acc[1][j] = fmaf(a1, wq[j], acc[1][j]);
                acc[2][j] = fmaf(a2, wq[j], acc[2][j]);
                acc[3][j] = fmaf(a3, wq[j], acc[3][j]);
            }
        }

        // relu + contract over this thread's 8 q's
        float uacc[4] = {0.f, 0.f, 0.f, 0.f};
        float vacc[4] = {0.f, 0.f, 0.f, 0.f};
        #pragma unroll
        for (int j = 0; j < 8; ++j) {
            const float bias = b1s[q0 + j];
            const float wa = w2as[q0 + j];
            const float wb = w2bs[q0 + j];
            #pragma unroll
            for (int i = 0; i < 4; ++i) {
                float g = fmaxf(acc[i][j] + bias, 0.f);
                uacc[i] += g * wa;
                vacc[i] += g * wb;
            }
        }

        // reduce over the 16 tx threads (lane groups of 16 within the wave)
        #pragma unroll
        for (int off = 8; off > 0; off >>= 1) {
            #pragma unroll
            for (int i = 0; i < 4; ++i) {
                uacc[i] += __shfl_down(uacc[i], off, 16);
                vacc[i] += __shfl_down(vacc[i], off, 16);
            }
        }
        if (tx == 0) {
            const int bbase = b0 + bb0;
            #pragma unroll
            for (int i = 0; i < 4; ++i) {
                ws[U_OFF + (size_t)(bbase + i) * DD + p] = uacc[i];
                ws[V_OFF + (size_t)(bbase + i) * DD + p] = vacc[i];
            }
        }
    }
}

// ---------------------------------------------------------------------------
// Kernel 3: per-batch score assembly + sigmoid.
//   out[b] = sigmoid( Adiff·u + (Ci-Cj)·v + b2*cntdiff )
// grid = 256, block = 64 (one wave per batch).
// ---------------------------------------------------------------------------
__global__ __launch_bounds__(64) void k3_final(
    const float* __restrict__ ws, const float* __restrict__ b2p,
    float* __restrict__ out)
{
    const int b = blockIdx.x;
    const int l = threadIdx.x;

    float s = 0.f;
    #pragma unroll
    for (int rep = 0; rep < 2; ++rep) {
        const int k = l + rep * 64;
        float A = 0.f, Ci = 0.f, Cj = 0.f;
        #pragma unroll
        for (int c = 0; c < NCHUNK; ++c) {
            A  += ws[PA_OFF  + ((size_t)c * BB + b) * DD + k];
            Ci += ws[PCI_OFF + ((size_t)c * BB + b) * DD + k];
            Cj += ws[PCJ_OFF + ((size_t)c * BB + b) * DD + k];
        }
        s += A * ws[U_OFF + (size_t)b * DD + k]
           + (Ci - Cj) * ws[V_OFF + (size_t)b * DD + k];
    }
    #pragma unroll
    for (int off = 32; off > 0; off >>= 1) s += __shfl_down(s, off, 64);

    if (l == 0) {
        float cnt = 0.f;
        #pragma unroll
        for (int c = 0; c < NCHUNK; ++c) cnt += ws[PCNT_OFF + c * BB + b];
        const float score = s + b2p[0] * cnt;   // SCALING_FACTOR == 1.0
        out[b] = 1.f / (1.f + expf(-score));
    }
}

extern "C" void kernel_launch(void* const* d_in, const int* in_sizes, int n_in,
                              void* d_out, int out_size, void* d_ws, size_t ws_size,
                              hipStream_t stream)
{
    const float* d   = (const float*)d_in[0];
    const float* si  = (const float*)d_in[1];
    const float* sj  = (const float*)d_in[2];
    const void*  mi  = d_in[3];
    const void*  mj  = d_in[4];
    const float* W1  = (const float*)d_in[5];
    const float* b1  = (const float*)d_in[6];
    const float* W2  = (const float*)d_in[7];
    const float* b2  = (const float*)d_in[8];
    float* ws  = (float*)d_ws;
    float* out = (float*)d_out;

    dim3 g1(NCHUNK, BB, 3);
    k1_stream<<<g1, 256, 0, stream>>>(d, si, sj, mi, mj, ws);
    dim3 g2(128, 2);
    k2_gemm<<<g2, 256, 0, stream>>>(d, W1, b1, W2, ws);
    k3_final<<<BB, 64, 0, stream>>>(ws, b2, out);
}

// Round 9
// 64.346 us; speedup vs baseline: 1.9074x; 1.6175x over previous
//
#include <hip/hip_runtime.h>
#include <math.h>

#define BB 256
#define NN 1024
#define DD 128
#define NCHUNK 4
#define ROWS (NN / NCHUNK)   // 256

// workspace layout (in floats)
#define PA_OFF   0
#define PCI_OFF  (NCHUNK*BB*DD)            // 131072
#define PCJ_OFF  (2*NCHUNK*BB*DD)          // 262144
#define PCNT_OFF (3*NCHUNK*BB*DD)          // 393216
#define U_OFF    (PCNT_OFF + NCHUNK*BB)    // 394240
#define V_OFF    (U_OFF + BB*DD)           // 427008
// total = 459776 floats = 1.84 MB

// ---------------------------------------------------------------------------
// Kernel 1: SPARSE masked streaming reductions over N, one array per block.
//   role 0: P_A[chunk][b][k]  = sum_n (mi-mj) * d[b,n,k]   (+ cnt via popc)
//   role 1: P_Ci[chunk][b][k] = sum_n  mi     * si[b,n,k]
//   role 2: P_Cj[chunk][b][k] = sum_n  mj     * sj[b,n,k]
// Rows with zero weight (~50%) are compacted away in LDS and NEVER LOADED —
// halves the 384 MB stream. Row = 512 B, so skips stay cacheline-efficient.
// grid = (NCHUNK, BB, 3), block = 256 (32 lanes x 8 row-groups).
// ---------------------------------------------------------------------------
__global__ __launch_bounds__(256) void k1_sparse(
    const float* __restrict__ d, const float* __restrict__ si,
    const float* __restrict__ sj, const void* __restrict__ miv,
    const void* __restrict__ mjv, float* __restrict__ ws)
{
    const int chunk = blockIdx.x;
    const int b     = blockIdx.y;
    const int role  = blockIdx.z;
    const int t     = threadIdx.x;
    const int lane  = t & 31;   // float4 column group: cols lane*4 .. +3
    const int rg    = t >> 5;   // row group 0..7
    const int wid   = t >> 6;   // wave 0..3
    const int l64   = t & 63;

    // ---- mask dtype auto-detect (bool bytes vs int32) ----
    __shared__ int s_mode;
    if (t == 0) s_mode = 0;
    __syncthreads();
    {
        const unsigned int* a = (const unsigned int*)miv;
        const unsigned int* c = (const unsigned int*)mjv;
        if ((a[t] | c[t]) > 1u) s_mode = 1;  // bytes of 0/1 packed in a word
    }
    __syncthreads();
    const bool bytes_mode = (s_mode != 0);

    // ---- stage weights, compute cnt (role 0), compact nonzero rows ----
    __shared__ float s_wc[ROWS];     // compacted weights
    __shared__ short s_idx[ROWS];    // compacted row indices (0..255)
    __shared__ int   s_wcnt[4];      // per-wave keep counts
    __shared__ int   s_woff[5];      // exclusive scan + total
    __shared__ int   s_cnt4[4];      // per-wave (sum mi - sum mj)

    const int    n0      = chunk * ROWS;
    const size_t rowbase = (size_t)b * NN;

    float w;
    {
        const size_t m = rowbase + (size_t)(n0 + t);
        float fi, fj;
        if (bytes_mode) {
            fi = (float)((const unsigned char*)miv)[m];
            fj = (float)((const unsigned char*)mjv)[m];
        } else {
            fi = (float)((const int*)miv)[m];
            fj = (float)((const int*)mjv)[m];
        }
        w = (role == 0) ? (fi - fj) : ((role == 1) ? fi : fj);
        if (role == 0) {
            const unsigned long long bi = __ballot(fi != 0.f);
            const unsigned long long bj = __ballot(fj != 0.f);
            if (l64 == 0) s_cnt4[wid] = __popcll(bi) - __popcll(bj);
        }
    }
    const bool keep = (w != 0.f);
    const unsigned long long ball = __ballot(keep);
    const int prefix = __popcll(ball & ((1ull << l64) - 1ull));
    if (l64 == 0) s_wcnt[wid] = __popcll(ball);
    __syncthreads();
    if (t == 0) {
        int a0 = 0;
        #pragma unroll
        for (int ww = 0; ww < 4; ++ww) { s_woff[ww] = a0; a0 += s_wcnt[ww]; }
        s_woff[4] = a0;
        if (role == 0)
            ws[PCNT_OFF + chunk * BB + b] =
                (float)(s_cnt4[0] + s_cnt4[1] + s_cnt4[2] + s_cnt4[3]);
    }
    __syncthreads();
    const int K    = s_woff[4];
    const int Kpad = (K + 31) & ~31;
    if (keep) {
        const int pos = s_woff[wid] + prefix;
        s_idx[pos] = (short)t;
        s_wc[pos]  = w;
    }
    for (int p = K + t; p < Kpad; p += 256) { s_idx[p] = 0; s_wc[p] = 0.f; }
    __syncthreads();

    const float* src = (role == 0) ? d : ((role == 1) ? si : sj);
    const size_t cbase = (rowbase + (size_t)n0) * (size_t)DD
                       + (size_t)lane * 4;

    float acc[4] = {0.f, 0.f, 0.f, 0.f};

    // 4 independent 512B-row loads in flight per thread batch; a wave's two
    // row-groups each cover one full 512 B row per load instruction.
    for (int i = 0; i < Kpad; i += 32) {
        int   r[4];
        float wv[4];
        #pragma unroll
        for (int u = 0; u < 4; ++u) {
            const int p = i + u * 8 + rg;
            r[u]  = s_idx[p];      // broadcast within row-group
            wv[u] = s_wc[p];
        }
        float4 v[4];
        #pragma unroll
        for (int u = 0; u < 4; ++u)
            v[u] = *(const float4*)(src + cbase + (size_t)r[u] * DD);
        #pragma unroll
        for (int u = 0; u < 4; ++u) {
            acc[0] = fmaf(wv[u], v[u].x, acc[0]);
            acc[1] = fmaf(wv[u], v[u].y, acc[1]);
            acc[2] = fmaf(wv[u], v[u].z, acc[2]);
            acc[3] = fmaf(wv[u], v[u].w, acc[3]);
        }
    }

    // ---- reduce the 8 row-groups (t strides of 32); [5] breaks bank stride
    __shared__ float red[256][5];
    #pragma unroll
    for (int i = 0; i < 4; ++i) red[t][i] = acc[i];
    __syncthreads();
    if (t < 128) {
        #pragma unroll
        for (int i = 0; i < 4; ++i) red[t][i] += red[t + 128][i];
    }
    __syncthreads();
    if (t < 64) {
        #pragma unroll
        for (int i = 0; i < 4; ++i) red[t][i] += red[t + 64][i];
    }
    __syncthreads();
    if (t < 32) {
        #pragma unroll
        for (int i = 0; i < 4; ++i) red[t][i] += red[t + 32][i];
        const size_t poff = ((role == 0) ? PA_OFF : ((role == 1) ? PCI_OFF
                                                                 : PCJ_OFF))
                          + ((size_t)chunk * BB + b) * DD;
        float* P = ws + poff;
        #pragma unroll
        for (int i = 0; i < 4; ++i) P[t * 4 + i] = red[t][i];
    }
}

// ---------------------------------------------------------------------------
// Kernel 2: M = relu(dm @ W1 + b1) fused with the w2 contraction:
//   u[b][p] = sum_q relu(dm[b]·W1[:,p*128+q] + b1[p*128+q]) * w2a[q]
//   v[b][p] = same with w2b
// grid = (128 p-tiles, 2 b-groups), block = 256 = 16 tx (q) x 16 ty (b).
// ---------------------------------------------------------------------------
__global__ __launch_bounds__(256) void k2_gemm(
    const float* __restrict__ d, const float* __restrict__ W1,
    const float* __restrict__ b1, const float* __restrict__ W2,
    float* __restrict__ ws)
{
    const int p  = blockIdx.x;      // output row of M (0..127)
    const int bg = blockIdx.y;      // batch group (0..1), 128 b each
    const int t  = threadIdx.x;
    const int tx = t & 15;          // q group: q0 = tx*8
    const int ty = t >> 4;          // b group: bb0 = ty*4

    __shared__ float w1s[128][128];  // [k][q]  64 KB
    __shared__ float dms[64][132];   // [bb][k] padded, ~34 KB
    __shared__ float b1s[128];
    __shared__ float w2as[128];
    __shared__ float w2bs[128];

    // stage W1 tile (coalesced: consecutive t -> consecutive q)
    for (int idx = t; idx < 128 * 128; idx += 256) {
        const int k = idx >> 7, q = idx & 127;
        w1s[k][q] = W1[(size_t)k * 16384 + p * 128 + q];
    }
    if (t < 128) {
        b1s[t]  = b1[p * 128 + t];
        w2as[t] = W2[t];
        w2bs[t] = W2[128 + t];
    }

    const int q0  = tx * 8;
    const int bb0 = ty * 4;

    for (int sc = 0; sc < 2; ++sc) {   // two sub-chunks of 64 batches
        const int b0 = bg * 128 + sc * 64;
        __syncthreads();   // protect dms reuse; also fences w1s staging (sc=0)
        for (int idx = t; idx < 64 * 128; idx += 256) {
            const int bb = idx >> 7, k = idx & 127;
            dms[bb][k] = d[(size_t)(b0 + bb) * NN * DD + k];  // d[b][0][k]
        }
        __syncthreads();

        float acc[4][8];
        #pragma unroll
        for (int i = 0; i < 4; ++i) {
            #pragma unroll
            for (int j = 0; j < 8; ++j) acc[i][j] = 0.f;
        }

        #pragma unroll 4
        for (int k = 0; k < 128; ++k) {
            float a0 = dms[bb0 + 0][k];
            float a1 = dms[bb0 + 1][k];
            float a2 = dms[bb0 + 2][k];
            float a3 = dms[bb0 + 3][k];
            const float4 wlo = *(const float4*)&w1s[k][q0];
            const float4 whi = *(const float4*)&w1s[k][q0 + 4];
            const float wq[8] = {wlo.x, wlo.y, wlo.z, wlo.w,
                                 whi.x, whi.y, whi.z, whi.w};
            #pragma unroll
            for (int j = 0; j < 8; ++j) {
                acc[0][j] = fmaf(a0, wq[j], acc[0][j]);
                acc[1][j] = fmaf(a1, wq[j], acc[1][j]);
                acc[2][j] = fmaf(a2, wq[j], acc[2][j]);
                acc[3][j] = fmaf(a3, wq[j], acc[3][j]);
            }
        }

        // relu + contract over this thread's 8 q's
        float uacc[4] = {0.f, 0.f, 0.f, 0.f};
        float vacc[4] = {0.f, 0.f, 0.f, 0.f};
        #pragma unroll
        for (int j = 0; j < 8; ++j) {
            const float bias = b1s[q0 + j];
            const float wa = w2as[q0 + j];
            const float wb = w2bs[q0 + j];
            #pragma unroll
            for (int i = 0; i < 4; ++i) {
                float g = fmaxf(acc[i][j] + bias, 0.f);
                uacc[i] += g * wa;
                vacc[i] += g * wb;
            }
        }

        // reduce over the 16 tx threads (lane groups of 16 within the wave)
        #pragma unroll
        for (int off = 8; off > 0; off >>= 1) {
            #pragma unroll
            for (int i = 0; i < 4; ++i) {
                uacc[i] += __shfl_down(uacc[i], off, 16);
                vacc[i] += __shfl_down(vacc[i], off, 16);
            }
        }
        if (tx == 0) {
            const int bbase = b0 + bb0;
            #pragma unroll
            for (int i = 0; i < 4; ++i) {
                ws[U_OFF + (size_t)(bbase + i) * DD + p] = uacc[i];
                ws[V_OFF + (size_t)(bbase + i) * DD + p] = vacc[i];
            }
        }
    }
}

// ---------------------------------------------------------------------------
// Kernel 3: per-batch score assembly + sigmoid.
//   out[b] = sigmoid( Adiff·u + (Ci-Cj)·v + b2*cntdiff )
// grid = 256, block = 64 (one wave per batch).
// ---------------------------------------------------------------------------
__global__ __launch_bounds__(64) void k3_final(
    const float* __restrict__ ws, const float* __restrict__ b2p,
    float* __restrict__ out)
{
    const int b = blockIdx.x;
    const int l = threadIdx.x;

    float s = 0.f;
    #pragma unroll
    for (int rep = 0; rep < 2; ++rep) {
        const int k = l + rep * 64;
        float A = 0.f, Ci = 0.f, Cj = 0.f;
        #pragma unroll
        for (int c = 0; c < NCHUNK; ++c) {
            A  += ws[PA_OFF  + ((size_t)c * BB + b) * DD + k];
            Ci += ws[PCI_OFF + ((size_t)c * BB + b) * DD + k];
            Cj += ws[PCJ_OFF + ((size_t)c * BB + b) * DD + k];
        }
        s += A * ws[U_OFF + (size_t)b * DD + k]
           + (Ci - Cj) * ws[V_OFF + (size_t)b * DD + k];
    }
    #pragma unroll
    for (int off = 32; off > 0; off >>= 1) s += __shfl_down(s, off, 64);

    if (l == 0) {
        float cnt = 0.f;
        #pragma unroll
        for (int c = 0; c < NCHUNK; ++c) cnt += ws[PCNT_OFF + c * BB + b];
        const float score = s + b2p[0] * cnt;   // SCALING_FACTOR == 1.0
        out[b] = 1.f / (1.f + expf(-score));
    }
}

extern "C" void kernel_launch(void* const* d_in, const int* in_sizes, int n_in,
                              void* d_out, int out_size, void* d_ws, size_t ws_size,
                              hipStream_t stream)
{
    const float* d   = (const float*)d_in[0];
    const float* si  = (const float*)d_in[1];
    const float* sj  = (const float*)d_in[2];
    const void*  mi  = d_in[3];
    const void*  mj  = d_in[4];
    const float* W1  = (const float*)d_in[5];
    const float* b1  = (const float*)d_in[6];
    const float* W2  = (const float*)d_in[7];
    const float* b2  = (const float*)d_in[8];
    float* ws  = (float*)d_ws;
    float* out = (float*)d_out;

    dim3 g1(NCHUNK, BB, 3);
    k1_sparse<<<g1, 256, 0, stream>>>(d, si, sj, mi, mj, ws);
    dim3 g2(128, 2);
    k2_gemm<<<g2, 256, 0, stream>>>(d, W1, b1, W2, ws);
    k3_final<<<BB, 64, 0, stream>>>(ws, b2, out);
}